// Round 11
// baseline (150.579 us; speedup 1.0000x reference)
//
#include <hip/hip_runtime.h>
#include <stdint.h>

#define Bv 16
#define Sv 512
#define Hv 12
#define Dv 64
#define HIDv 768

typedef __attribute__((ext_vector_type(8))) short bf8_t;
typedef __attribute__((ext_vector_type(4))) float f32x4;
typedef __attribute__((ext_vector_type(8))) unsigned short u16x8;
typedef __attribute__((ext_vector_type(4))) unsigned short u16x4;

__device__ __forceinline__ float b2f(unsigned short u){
    union { unsigned int i; float f; } x; x.i = ((unsigned int)u) << 16; return x.f;
}
__device__ __forceinline__ unsigned short f2b(float f){
    union { float f; unsigned int i; } x; x.f = f;
    unsigned int r = x.i + 0x7fff + ((x.i >> 16) & 1);
    return (unsigned short)(r >> 16);
}
__device__ __forceinline__ void gload16(const unsigned short* g, unsigned short* l){
    __builtin_amdgcn_global_load_lds(
        (const __attribute__((address_space(1))) void*)g,
        (__attribute__((address_space(3))) void*)l, 16, 0, 0);
}

#define RS 0.18033688f          /* 0.125 * log2(e) */
#define LOG2E 1.44269504f

// ---------------------------------------------------------------------------
// All f32->bf16 conversions in one launch: hs (2048 blks), Wq/Wk/Wv (1728),
// dist_emb (64). Grid = 3840.
// ---------------------------------------------------------------------------
__global__ __launch_bounds__(256) void cvt_all(
    const float* __restrict__ hs,
    const float* __restrict__ Wq, const float* __restrict__ Wk, const float* __restrict__ Wv,
    const float* __restrict__ de,
    unsigned short* __restrict__ Xb, unsigned short* __restrict__ Wb,
    unsigned short* __restrict__ deb)
{
    const int id = blockIdx.x, t = threadIdx.x;
    if (id < 2048){
        for (int i = id*256 + t; i < 1572864; i += 2048*256){
            float4 v = ((const float4*)hs)[i];
            u16x4 o = { f2b(v.x), f2b(v.y), f2b(v.z), f2b(v.w) };
            ((u16x4*)Xb)[i] = o;
        }
    } else if (id < 3776){
        int i = (id - 2048)*256 + t;                 // < 442368
        int which = i / 147456, j = i - which*147456;
        const float* src = which == 0 ? Wq : (which == 1 ? Wk : Wv);
        float4 v = ((const float4*)src)[j];
        u16x4 o = { f2b(v.x), f2b(v.y), f2b(v.z), f2b(v.w) };
        ((u16x4*)Wb)[i] = o;
    } else {
        int i = (id - 3776)*256 + t;
        if (i < 16368){
            float4 v = ((const float4*)de)[i];
            u16x4 o = { f2b(v.x), f2b(v.y), f2b(v.z), f2b(v.w) };
            ((u16x4*)deb)[i] = o;
        }
    }
}

// ---------------------------------------------------------------------------
// FUSED: qkv projection (1152 blocks) + lvl-bias pre-tiling (1024 blocks).
// Grid = 2176, INTERLEAVED (even ids -> qkv, odd -> prep for ids < 2048) so
// both kinds are co-resident from dispatch start: qkv is compute-bound,
// prep is pure HBM BW (134MB int reads) -> overlap instead of serialize.
// ---------------------------------------------------------------------------
__global__ __launch_bounds__(256,3) void qkv_prep(
    const unsigned short* __restrict__ Xb,
    const unsigned short* __restrict__ Wb,
    const float* __restrict__ bq, const float* __restrict__ bk, const float* __restrict__ bv,
    unsigned short* __restrict__ qkb,
    unsigned short* __restrict__ vtb,
    const int* __restrict__ cmat, const int* __restrict__ wmat,
    const float* __restrict__ mask, const float* __restrict__ ce, const float* __restrict__ we,
    unsigned short* __restrict__ lvlt)
{
    __shared__ unsigned short Ab[128*40];
    __shared__ unsigned short Bb[128*40];
    __shared__ float tab[64];

    const int t = threadIdx.x;
    const int w = t >> 6, lane = t & 63, g = lane >> 4, cc = lane & 15;

    const int id = blockIdx.x;
    const bool is_prep = (id < 2048) && (id & 1);

    if (is_prep){
        // ---------------- prep_bias path (verified R9 math) ----------------
        const int blk = id >> 1;                  // 0..1023
        const int c8 = blk & 7, lt = (blk >> 3) & 7, b = blk >> 6;
        if (t < 64) tab[t] = (0.5f*ce[t>>3] + 0.5f*we[t&7]) * RS;
        __syncthreads();
        const int ll = lt*64 + w*16 + cc;
        const int* crow = cmat + ((size_t)b*512 + ll)*512;
        const int* wrow = wmat + ((size_t)b*512 + ll)*512;
        const float* mrow = mask + (size_t)b*512;
        unsigned short o[16];
        #pragma unroll
        for (int i = 0; i < 4; ++i){
            int rb = c8*64 + i*16 + 4*g;
            int4 c4 = *(const int4*)(crow + rb);
            int4 w4 = *(const int4*)(wrow + rb);
            float4 mv = *(const float4*)(mrow + rb);
            o[i*4 + 0] = f2b(tab[(c4.x<<3)|w4.x] + mv.x * LOG2E);
            o[i*4 + 1] = f2b(tab[(c4.y<<3)|w4.y] + mv.y * LOG2E);
            o[i*4 + 2] = f2b(tab[(c4.z<<3)|w4.z] + mv.z * LOG2E);
            o[i*4 + 3] = f2b(tab[(c4.w<<3)|w4.w] + mv.w * LOG2E);
        }
        unsigned short* dst = lvlt + ((size_t)blk*256 + t)*16;
        *(u16x8*)dst       = *(u16x8*)&o[0];
        *(u16x8*)(dst + 8) = *(u16x8*)&o[8];
        return;
    }

    // ---------------- qkv path (verified since R2) ----------------
    const int qb = (id < 2048) ? (id >> 1) : (id - 1024);   // 0..1151
    const int wm = w >> 1, wn = w & 1;
    const int m0 = (qb & 63) * 128;
    const int n0 = (qb >> 6) * 128;

    const f32x4 fz = {0.f,0.f,0.f,0.f};
    f32x4 acc[4][4];
    #pragma unroll
    for (int i = 0; i < 4; ++i)
        #pragma unroll
        for (int j = 0; j < 4; ++j) acc[i][j] = fz;

    u16x8 pa[2], pb[2];
    #pragma unroll
    for (int r = 0; r < 2; ++r){
        int chunk = t + r*256; int row = chunk >> 2; int ch = chunk & 3;
        pa[r] = *(const u16x8*)(Xb + (size_t)(m0+row)*768 + ch*8);
        pb[r] = *(const u16x8*)(Wb + (size_t)(n0+row)*768 + ch*8);
    }
    for (int k0 = 0; k0 < 768; k0 += 32){
        __syncthreads();
        #pragma unroll
        for (int r = 0; r < 2; ++r){
            int chunk = t + r*256; int row = chunk >> 2; int ch = chunk & 3;
            *(u16x8*)&Ab[row*40 + ch*8] = pa[r];
            *(u16x8*)&Bb[row*40 + ch*8] = pb[r];
        }
        __syncthreads();
        if (k0 + 32 < 768){
            #pragma unroll
            for (int r = 0; r < 2; ++r){
                int chunk = t + r*256; int row = chunk >> 2; int ch = chunk & 3;
                pa[r] = *(const u16x8*)(Xb + (size_t)(m0+row)*768 + (k0+32) + ch*8);
                pb[r] = *(const u16x8*)(Wb + (size_t)(n0+row)*768 + (k0+32) + ch*8);
            }
        }
        bf8_t af[4], bfr[4];
        #pragma unroll
        for (int mf = 0; mf < 4; ++mf)
            af[mf] = *(const bf8_t*)&Ab[(wm*64 + mf*16 + cc)*40 + g*8];
        #pragma unroll
        for (int nf = 0; nf < 4; ++nf)
            bfr[nf] = *(const bf8_t*)&Bb[(wn*64 + nf*16 + cc)*40 + g*8];
        #pragma unroll
        for (int mf = 0; mf < 4; ++mf)
            #pragma unroll
            for (int nf = 0; nf < 4; ++nf)
                acc[mf][nf] = __builtin_amdgcn_mfma_f32_16x16x32_bf16(af[mf], bfr[nf], acc[mf][nf], 0,0,0);
    }

    const int b  = m0 >> 9;
    const int s0 = (m0 & 511) + wm*64;
    const int nbase = n0 + wn*64;
    const int proj = nbase / 768;
    const int nin0 = nbase % 768;
    const float* bias = proj == 0 ? bq : (proj == 1 ? bk : bv);
    #pragma unroll
    for (int nf = 0; nf < 4; ++nf){
        int nin = nin0 + nf*16 + cc;
        int h = nin >> 6, d = nin & 63;
        float bvv = bias[nin];
        #pragma unroll
        for (int mf = 0; mf < 4; ++mf){
            int s = s0 + mf*16 + g*4;
            if (proj < 2){
                unsigned short* base = qkb + (((((size_t)proj*Bv + b)*Hv + h)*Sv + s)*Dv + d);
                #pragma unroll
                for (int r2 = 0; r2 < 4; ++r2)
                    base[(size_t)r2*Dv] = f2b(acc[mf][nf][r2] + bvv);
            } else {
                u16x4 o = { f2b(acc[mf][nf][0]+bvv), f2b(acc[mf][nf][1]+bvv),
                            f2b(acc[mf][nf][2]+bvv), f2b(acc[mf][nf][3]+bvv) };
                *(u16x4*)(vtb + ((((size_t)b*Hv + h)*Dv + d)*Sv + s)) = o;
            }
        }
    }
}

// ---------------------------------------------------------------------------
// Fused attention v10 = R9 + t1 transposed to [ll][rl]:
// scatter still 2x write2/i (consecutive cols, masks only i=0/4, -4-float
// headroom absorbs the -1 overhang, 16B alignment kept), gather becomes
// ONE ds_read_b128 per i (4 ops vs 8 read2).
// ---------------------------------------------------------------------------
__global__ __launch_bounds__(256,2) void attn(
    const unsigned short* __restrict__ qkb,
    const unsigned short* __restrict__ vtb,
    const unsigned short* __restrict__ deb,    // [1024][64] bf16 (row 1023 = pad)
    const unsigned short* __restrict__ lvlt,   // fragment-tiled lvl bias
    float* __restrict__ out)
{
    __shared__ __align__(16) unsigned short sm[37648];
    unsigned short* ks  = sm;                        // [64][64] swz    8192 B
    unsigned short* vsq = sm + 4096;                 // [64][64] swz    8192 B
    unsigned short* des = sm + 8192;                 // [128][64] swz  16384 B
    float*          t1t = (float*)(sm + 16384) + 4;  // [64][68]+hdrm  17440 B
    float*          t2c = (float*)(sm + 25104);      // [64][66] f32   16896 B
    unsigned int*   Pb  = (unsigned int*)(sm + 33552); // [64][32] u32  8192 B

    const int t = threadIdx.x, w = t >> 6, lane = t & 63, g = lane >> 4, cc = lane & 15;
    const int lr8 = lane >> 3, lc8 = lane & 7;

    // b-based XCD remap: all blocks of batch b on XCD b%8
    const int wg = blockIdx.x;
    const int xcd = wg & 7, inner = wg >> 3;
    const int b  = ((inner & 1) << 3) | xcd;
    const int r2 = inner >> 1;
    const int h  = r2 % 12, lt = r2 / 12;
    const int l0 = lt * 64;

    const unsigned short* qp = qkb + ((((size_t)0*Bv + b)*Hv + h)*Sv + l0)*Dv;
    const unsigned short* kp = qkb + ((((size_t)1*Bv + b)*Hv + h)*Sv)*Dv;
    const unsigned short* vp = vtb + (((size_t)b*Hv + h)*Dv)*Sv;
    const unsigned short* lvbase = lvlt + (((size_t)b*8 + lt)*8)*256*16 + (size_t)t*16;

    const f32x4 fz = {0.f,0.f,0.f,0.f};
    const int R   = 3 - w;               // T2 rl-block (jb range matches T1's)
    const int llm = w*16 + cc;           // lane's score/softmax/P row
    const int sw  = (cc & 7) << 2;       // P column swizzle
    const int s_t2 = 4*g + cc;           // t2 mask helper
    const int Kb  = cc - 4*g + 63;       // t1 col base (minus 16*i)

    auto stage_k = [&](int r0){
        #pragma unroll
        for (int j = 0; j < 2; ++j){
            int row = w*16 + j*8 + lr8;
            int ch  = lc8 ^ (row & 7);
            gload16(kp + (size_t)(r0 + row)*64 + ch*8, ks + w*1024 + j*512);
        }
    };
    auto stage_de = [&](int r0){
        const int base = l0 - r0 + 448;
        #pragma unroll
        for (int j = 0; j < 4; ++j){
            int row = w*32 + j*8 + lr8;
            int gr = base + row; if (gr > 1022) gr = 1022;
            int ch  = lc8 ^ (row & 7);
            gload16(deb + (size_t)gr*64 + ch*8, des + w*2048 + j*512);
        }
    };
    auto stage_v0 = [&](){
        #pragma unroll
        for (int j = 0; j < 2; ++j){
            int row = w*16 + j*8 + lr8;
            int ch  = lc8 ^ (row & 7);
            gload16(vp + (size_t)row*512 + ch*8, vsq + w*1024 + j*512);
        }
    };

    // ---- prologue: Q frags from global; stage chunk-0
    bf8_t qf0, qf1;
    {
        int qrow = w*16 + cc;
        qf0 = *(const bf8_t*)(qp + (size_t)qrow*64 + g*8);
        qf1 = *(const bf8_t*)(qp + (size_t)qrow*64 + (g+4)*8);
    }
    stage_k(0); stage_de(0); stage_v0();
    __syncthreads();

    float l_run = 0.f;
    f32x4 ctx[4] = {fz,fz,fz,fz};

    for (int c8 = 0; c8 < 8; ++c8){
        const int r0 = c8 * 64;
        u16x8 lva = *(const u16x8*)(lvbase + (size_t)c8*256*16);
        u16x8 lvb = *(const u16x8*)(lvbase + (size_t)c8*256*16 + 8);

        // ---- MFMA phase: swapped scores + band with write2 scatters ----
        __builtin_amdgcn_s_setprio(1);
        f32x4 accs[4];                         // C[rl][ll]: rl=i16+4g+reg, ll=llm
        bf8_t kf0, kf1;
        #pragma unroll
        for (int i = 0; i < 4; ++i){
            int row = i*16 + cc;
            bf8_t b0 = *(const bf8_t*)&ks[row*64 + ((g       ^ (row & 7))*8)];
            bf8_t b1 = *(const bf8_t*)&ks[row*64 + (((g + 4) ^ (row & 7))*8)];
            if (i == R){ kf0 = b0; kf1 = b1; }
            f32x4 a = fz;
            a = __builtin_amdgcn_mfma_f32_16x16x32_bf16(b0, qf0, a, 0,0,0);
            a = __builtin_amdgcn_mfma_f32_16x16x32_bf16(b1, qf1, a, 0,0,0);
            accs[i] = a;
        }
        #pragma unroll
        for (int i = 0; i < 5; ++i){
            int jrow = (w + i)*16 + cc;
            bf8_t d0 = *(const bf8_t*)&des[jrow*64 + ((g       ^ (jrow & 7))*8)];
            bf8_t d1 = *(const bf8_t*)&des[jrow*64 + (((g + 4) ^ (jrow & 7))*8)];
            f32x4 a1 = fz, a2 = fz;                 // a1=C[jb][ll], a2=C[rl][jb]
            a1 = __builtin_amdgcn_mfma_f32_16x16x32_bf16(d0, qf0, a1, 0,0,0);
            a1 = __builtin_amdgcn_mfma_f32_16x16x32_bf16(d1, qf1, a1, 0,0,0);
            a2 = __builtin_amdgcn_mfma_f32_16x16x32_bf16(kf0, d0, a2, 0,0,0);
            a2 = __builtin_amdgcn_mfma_f32_16x16x32_bf16(kf1, d1, a2, 0,0,0);

            // t1 scatter (transposed): t1t[llm][rl], rl = K - reg
            {
                int K = Kb - 16*i;
                float* tb = t1t + llm*68 + K;
                bool mA = (i != 0 || K <= 64) && (i != 4 || K >= 0);
                bool mB = (i != 0 || K <= 66) && (i != 4 || K >= 2);
                if (mA){ tb[-1] = a1[1]; tb[0]  = a1[0]; }
                if (mB){ tb[-3] = a1[3]; tb[-2] = a1[2]; }
            }
            // t2 scatter: row = rl, col = (rl + jb - 63) + 1 (verified R9)
            {
                float* tb = t2c + (R*16 + 4*g)*66 + (16*i + 4*g + cc - 14);
                bool mA = (i != 0 || s_t2 >= 14) && (i != 4 || s_t2 <= 14);
                bool mB = (i != 0 || s_t2 >= 12) && (i != 4 || s_t2 <= 12);
                if (mA){ tb[0]   = a2[0]; tb[67]  = a2[1]; }
                if (mB){ tb[134] = a2[2]; tb[201] = a2[3]; }
            }
        }
        __builtin_amdgcn_s_setprio(0);
        __syncthreads();                       // B3: band visible; ks/des dead

        // issue next-chunk staging: K/DE direct-to-LDS, V to registers (T14)
        u16x8 pv0, pv1;
        if (c8 < 7){
            stage_k(r0 + 64); stage_de(r0 + 64);
            int row0 = w*16 + lr8,  ch0 = lc8 ^ (row0 & 7);
            int row1 = row0 + 8,    ch1 = lc8 ^ (row1 & 7);
            pv0 = *(const u16x8*)(vp + (size_t)row0*512 + (r0+64) + ch0*8);
            pv1 = *(const u16x8*)(vp + (size_t)row1*512 + (r0+64) + ch1*8);
        }

        // ---- epilogue: b128 t1 gathers, read2 t2 gathers, exp2, packed P ----
        float ps = 0.f;
        #pragma unroll
        for (int i = 0; i < 4; ++i){
            f32x4 t1v = *(const f32x4*)&t1t[llm*68 + 16*i + 4*g];
            const float* g2 = t2c + (i*16 + 4*g)*66 + llm + 1;
            float t20 = g2[0], t21 = g2[66], t22 = g2[132], t23 = g2[198];
            float lv0 = b2f(i < 2 ? (unsigned short)lva[i*4+0] : (unsigned short)lvb[(i-2)*4+0]);
            float lv1 = b2f(i < 2 ? (unsigned short)lva[i*4+1] : (unsigned short)lvb[(i-2)*4+1]);
            float lv2 = b2f(i < 2 ? (unsigned short)lva[i*4+2] : (unsigned short)lvb[(i-2)*4+2]);
            float lv3 = b2f(i < 2 ? (unsigned short)lva[i*4+3] : (unsigned short)lvb[(i-2)*4+3]);
            float p0 = __builtin_amdgcn_exp2f((accs[i][0] + t1v[0] + t20) * RS + lv0);
            float p1 = __builtin_amdgcn_exp2f((accs[i][1] + t1v[1] + t21) * RS + lv1);
            float p2 = __builtin_amdgcn_exp2f((accs[i][2] + t1v[2] + t22) * RS + lv2);
            float p3 = __builtin_amdgcn_exp2f((accs[i][3] + t1v[3] + t23) * RS + lv3);
            ps += (p0 + p1) + (p2 + p3);
            unsigned int prs0 = (unsigned)f2b(p0) | ((unsigned)f2b(p1) << 16);
            unsigned int prs1 = (unsigned)f2b(p2) | ((unsigned)f2b(p3) << 16);
            uint2 pr = { prs0, prs1 };
            *(uint2*)&Pb[llm*32 + ((i*8 + 2*g) ^ sw)] = pr;
        }
        ps += __shfl_xor(ps, 16);
        ps += __shfl_xor(ps, 32);
        l_run += ps;
        __builtin_amdgcn_wave_barrier();       // keep P writes before PV reads

        // ---- PV: A = P (packed, swizzled), B = V ----
        __builtin_amdgcn_s_setprio(1);
        #pragma unroll
        for (int kh = 0; kh < 2; ++kh){
            bf8_t pf = *(const bf8_t*)&Pb[llm*32 + ((16*kh + 4*g) ^ sw)];
            #pragma unroll
            for (int nf = 0; nf < 4; ++nf){
                int vr = nf*16 + cc;
                bf8_t vf = *(const bf8_t*)&vsq[vr*64 + (((g + 4*kh) ^ (vr & 7))*8)];
                ctx[nf] = __builtin_amdgcn_mfma_f32_16x16x32_bf16(pf, vf, ctx[nf], 0,0,0);
            }
        }
        __builtin_amdgcn_s_setprio(0);

        if (c8 < 7){
            __syncthreads();                   // B1: PV done; K/DE gloads drained
            *(u16x8*)&vsq[w*1024 +       lane*8] = pv0;
            *(u16x8*)&vsq[w*1024 + 512 + lane*8] = pv1;
            __syncthreads();                   // B2: new V visible
        }
    }

    // redistribute l_run (per-cc row sums) to the ctx row layout (4g+reg)
    float linv[4];
    #pragma unroll
    for (int reg = 0; reg < 4; ++reg)
        linv[reg] = 1.0f / __shfl(l_run, 4*g + reg);

    #pragma unroll
    for (int nf = 0; nf < 4; ++nf){
        #pragma unroll
        for (int reg = 0; reg < 4; ++reg){
            int ll = w*16 + 4*g + reg;
            out[((size_t)b*Sv + l0 + ll)*HIDv + h*64 + nf*16 + cc] = ctx[nf][reg] * linv[reg];
        }
    }
}

extern "C" void kernel_launch(void* const* d_in, const int* in_sizes, int n_in,
                              void* d_out, int out_size, void* d_ws, size_t ws_size,
                              hipStream_t stream)
{
    const float* hs   = (const float*)d_in[0];
    const float* mask = (const float*)d_in[1];
    const int*   cmat = (const int*)  d_in[2];
    const int*   wmat = (const int*)  d_in[3];
    const float* Wq   = (const float*)d_in[4];
    const float* bq   = (const float*)d_in[5];
    const float* Wk   = (const float*)d_in[6];
    const float* bk   = (const float*)d_in[7];
    const float* Wv   = (const float*)d_in[8];
    const float* bv   = (const float*)d_in[9];
    const float* de   = (const float*)d_in[10];
    const float* ce   = (const float*)d_in[11];
    const float* we   = (const float*)d_in[12];
    float* out = (float*)d_out;

    unsigned short* Xb   = (unsigned short*)d_ws;        // 8192*768
    unsigned short* Wb   = Xb   + 6291456;               // 2304*768
    unsigned short* deb  = Wb   + 1769472;               // 1023*64 (+ pad)
    unsigned short* qkb  = deb  + 65536;                 // 2*16*12*512*64
    unsigned short* vtb  = qkb  + 12582912;              // 16*12*64*512
    unsigned short* lvlt = vtb  + 6291456;               // 1024*256*16

    cvt_all<<<3840, 256, 0, stream>>>(hs, Wq, Wk, Wv, de, Xb, Wb, deb);
    qkv_prep<<<2176, 256, 0, stream>>>(Xb, Wb, bq, bk, bv, qkb, vtb,
                                       cmat, wmat, mask, ce, we, lvlt);
    attn<<<1536, 256, 0, stream>>>(qkb, vtb, deb, lvlt, out);
}

// Round 12
// 133.113 us; speedup vs baseline: 1.1312x; 1.1312x over previous
//
#include <hip/hip_runtime.h>
#include <stdint.h>

#define Bv 16
#define Sv 512
#define Hv 12
#define Dv 64
#define HIDv 768

typedef __attribute__((ext_vector_type(8))) short bf8_t;
typedef __attribute__((ext_vector_type(4))) float f32x4;
typedef __attribute__((ext_vector_type(8))) unsigned short u16x8;
typedef __attribute__((ext_vector_type(4))) unsigned short u16x4;

__device__ __forceinline__ float b2f(unsigned short u){
    union { unsigned int i; float f; } x; x.i = ((unsigned int)u) << 16; return x.f;
}
__device__ __forceinline__ unsigned short f2b(float f){
    union { float f; unsigned int i; } x; x.f = f;
    unsigned int r = x.i + 0x7fff + ((x.i >> 16) & 1);
    return (unsigned short)(r >> 16);
}
__device__ __forceinline__ void gload16(const unsigned short* g, unsigned short* l){
    __builtin_amdgcn_global_load_lds(
        (const __attribute__((address_space(1))) void*)g,
        (__attribute__((address_space(3))) void*)l, 16, 0, 0);
}

#define RS 0.18033688f          /* 0.125 * log2(e) */
#define LOG2E 1.44269504f

// ---------------------------------------------------------------------------
// All f32->bf16 conversions in one launch (verified R11).
// ---------------------------------------------------------------------------
__global__ __launch_bounds__(256) void cvt_all(
    const float* __restrict__ hs,
    const float* __restrict__ Wq, const float* __restrict__ Wk, const float* __restrict__ Wv,
    const float* __restrict__ de,
    unsigned short* __restrict__ Xb, unsigned short* __restrict__ Wb,
    unsigned short* __restrict__ deb)
{
    const int id = blockIdx.x, t = threadIdx.x;
    if (id < 2048){
        for (int i = id*256 + t; i < 1572864; i += 2048*256){
            float4 v = ((const float4*)hs)[i];
            u16x4 o = { f2b(v.x), f2b(v.y), f2b(v.z), f2b(v.w) };
            ((u16x4*)Xb)[i] = o;
        }
    } else if (id < 3776){
        int i = (id - 2048)*256 + t;                 // < 442368
        int which = i / 147456, j = i - which*147456;
        const float* src = which == 0 ? Wq : (which == 1 ? Wk : Wv);
        float4 v = ((const float4*)src)[j];
        u16x4 o = { f2b(v.x), f2b(v.y), f2b(v.z), f2b(v.w) };
        ((u16x4*)Wb)[i] = o;
    } else {
        int i = (id - 3776)*256 + t;
        if (i < 16368){
            float4 v = ((const float4*)de)[i];
            u16x4 o = { f2b(v.x), f2b(v.y), f2b(v.z), f2b(v.w) };
            ((u16x4*)deb)[i] = o;
        }
    }
}

// ---------------------------------------------------------------------------
// lvl bias pre-tiled to the SWAPPED attn fragment layout (verified R9/R11).
// STANDALONE again: fusing with qkv poisoned regalloc (R11: VGPR 64 + spills).
// ---------------------------------------------------------------------------
__global__ __launch_bounds__(256) void prep_bias_t(
    const int* __restrict__ cmat, const int* __restrict__ wmat,
    const float* __restrict__ mask, const float* __restrict__ ce, const float* __restrict__ we,
    unsigned short* __restrict__ lvlt)
{
    __shared__ float tab[64];
    const int t = threadIdx.x;
    const int blk = blockIdx.x;
    const int c8 = blk & 7, lt = (blk >> 3) & 7, b = blk >> 6;
    if (t < 64) tab[t] = (0.5f*ce[t>>3] + 0.5f*we[t&7]) * RS;
    __syncthreads();
    const int w = t >> 6, lane = t & 63, g = lane >> 4, cc = lane & 15;
    const int ll = lt*64 + w*16 + cc;
    const int* crow = cmat + ((size_t)b*512 + ll)*512;
    const int* wrow = wmat + ((size_t)b*512 + ll)*512;
    const float* mrow = mask + (size_t)b*512;
    unsigned short o[16];
    #pragma unroll
    for (int i = 0; i < 4; ++i){
        int rb = c8*64 + i*16 + 4*g;
        int4 c4 = *(const int4*)(crow + rb);
        int4 w4 = *(const int4*)(wrow + rb);
        float4 mv = *(const float4*)(mrow + rb);
        o[i*4 + 0] = f2b(tab[(c4.x<<3)|w4.x] + mv.x * LOG2E);
        o[i*4 + 1] = f2b(tab[(c4.y<<3)|w4.y] + mv.y * LOG2E);
        o[i*4 + 2] = f2b(tab[(c4.z<<3)|w4.z] + mv.z * LOG2E);
        o[i*4 + 3] = f2b(tab[(c4.w<<3)|w4.w] + mv.w * LOG2E);
    }
    unsigned short* dst = lvlt + ((size_t)blk*256 + t)*16;
    *(u16x8*)dst       = *(u16x8*)&o[0];
    *(u16x8*)(dst + 8) = *(u16x8*)&o[8];
}

// ---------------------------------------------------------------------------
// QKV projection (verified R2-R9 standalone form):
// Q,K -> [proj][b][h][s][d], V -> [b][h][d][s]
// ---------------------------------------------------------------------------
__global__ __launch_bounds__(256,3) void qkv_gemm(
    const unsigned short* __restrict__ Xb,
    const unsigned short* __restrict__ Wb,
    const float* __restrict__ bq, const float* __restrict__ bk, const float* __restrict__ bv,
    unsigned short* __restrict__ qkb,
    unsigned short* __restrict__ vtb)
{
    __shared__ unsigned short Ab[128*40];
    __shared__ unsigned short Bb[128*40];
    const int t = threadIdx.x;
    const int w = t >> 6, lane = t & 63, g = lane >> 4, cc = lane & 15;
    const int wm = w >> 1, wn = w & 1;
    const int m0 = blockIdx.x * 128;
    const int n0 = blockIdx.y * 128;

    const f32x4 fz = {0.f,0.f,0.f,0.f};
    f32x4 acc[4][4];
    #pragma unroll
    for (int i = 0; i < 4; ++i)
        #pragma unroll
        for (int j = 0; j < 4; ++j) acc[i][j] = fz;

    u16x8 pa[2], pb[2];
    #pragma unroll
    for (int r = 0; r < 2; ++r){
        int chunk = t + r*256; int row = chunk >> 2; int ch = chunk & 3;
        pa[r] = *(const u16x8*)(Xb + (size_t)(m0+row)*768 + ch*8);
        pb[r] = *(const u16x8*)(Wb + (size_t)(n0+row)*768 + ch*8);
    }
    for (int k0 = 0; k0 < 768; k0 += 32){
        __syncthreads();
        #pragma unroll
        for (int r = 0; r < 2; ++r){
            int chunk = t + r*256; int row = chunk >> 2; int ch = chunk & 3;
            *(u16x8*)&Ab[row*40 + ch*8] = pa[r];
            *(u16x8*)&Bb[row*40 + ch*8] = pb[r];
        }
        __syncthreads();
        if (k0 + 32 < 768){
            #pragma unroll
            for (int r = 0; r < 2; ++r){
                int chunk = t + r*256; int row = chunk >> 2; int ch = chunk & 3;
                pa[r] = *(const u16x8*)(Xb + (size_t)(m0+row)*768 + (k0+32) + ch*8);
                pb[r] = *(const u16x8*)(Wb + (size_t)(n0+row)*768 + (k0+32) + ch*8);
            }
        }
        bf8_t af[4], bfr[4];
        #pragma unroll
        for (int mf = 0; mf < 4; ++mf)
            af[mf] = *(const bf8_t*)&Ab[(wm*64 + mf*16 + cc)*40 + g*8];
        #pragma unroll
        for (int nf = 0; nf < 4; ++nf)
            bfr[nf] = *(const bf8_t*)&Bb[(wn*64 + nf*16 + cc)*40 + g*8];
        #pragma unroll
        for (int mf = 0; mf < 4; ++mf)
            #pragma unroll
            for (int nf = 0; nf < 4; ++nf)
                acc[mf][nf] = __builtin_amdgcn_mfma_f32_16x16x32_bf16(af[mf], bfr[nf], acc[mf][nf], 0,0,0);
    }

    const int b  = m0 >> 9;
    const int s0 = (m0 & 511) + wm*64;
    const int nbase = n0 + wn*64;
    const int proj = nbase / 768;
    const int nin0 = nbase % 768;
    const float* bias = proj == 0 ? bq : (proj == 1 ? bk : bv);
    #pragma unroll
    for (int nf = 0; nf < 4; ++nf){
        int nin = nin0 + nf*16 + cc;
        int h = nin >> 6, d = nin & 63;
        float bvv = bias[nin];
        #pragma unroll
        for (int mf = 0; mf < 4; ++mf){
            int s = s0 + mf*16 + g*4;
            if (proj < 2){
                unsigned short* base = qkb + (((((size_t)proj*Bv + b)*Hv + h)*Sv + s)*Dv + d);
                #pragma unroll
                for (int r2 = 0; r2 < 4; ++r2)
                    base[(size_t)r2*Dv] = f2b(acc[mf][nf][r2] + bvv);
            } else {
                u16x4 o = { f2b(acc[mf][nf][0]+bvv), f2b(acc[mf][nf][1]+bvv),
                            f2b(acc[mf][nf][2]+bvv), f2b(acc[mf][nf][3]+bvv) };
                *(u16x4*)(vtb + ((((size_t)b*Hv + h)*Dv + d)*Sv + s)) = o;
            }
        }
    }
}

// ---------------------------------------------------------------------------
// Fused attention v10 (verified R11): swapped scores, t1 transposed [ll][rl]
// (b128 gathers), t2 read2 gathers, packed-u32 swizzled P, T14 V restage.
// ---------------------------------------------------------------------------
__global__ __launch_bounds__(256,2) void attn(
    const unsigned short* __restrict__ qkb,
    const unsigned short* __restrict__ vtb,
    const unsigned short* __restrict__ deb,    // [1024][64] bf16 (row 1023 = pad)
    const unsigned short* __restrict__ lvlt,   // fragment-tiled lvl bias
    float* __restrict__ out)
{
    __shared__ __align__(16) unsigned short sm[37648];
    unsigned short* ks  = sm;                        // [64][64] swz    8192 B
    unsigned short* vsq = sm + 4096;                 // [64][64] swz    8192 B
    unsigned short* des = sm + 8192;                 // [128][64] swz  16384 B
    float*          t1t = (float*)(sm + 16384) + 4;  // [64][68]+hdrm  17440 B
    float*          t2c = (float*)(sm + 25104);      // [64][66] f32   16896 B
    unsigned int*   Pb  = (unsigned int*)(sm + 33552); // [64][32] u32  8192 B

    const int t = threadIdx.x, w = t >> 6, lane = t & 63, g = lane >> 4, cc = lane & 15;
    const int lr8 = lane >> 3, lc8 = lane & 7;

    // b-based XCD remap: all blocks of batch b on XCD b%8
    const int wg = blockIdx.x;
    const int xcd = wg & 7, inner = wg >> 3;
    const int b  = ((inner & 1) << 3) | xcd;
    const int r2 = inner >> 1;
    const int h  = r2 % 12, lt = r2 / 12;
    const int l0 = lt * 64;

    const unsigned short* qp = qkb + ((((size_t)0*Bv + b)*Hv + h)*Sv + l0)*Dv;
    const unsigned short* kp = qkb + ((((size_t)1*Bv + b)*Hv + h)*Sv)*Dv;
    const unsigned short* vp = vtb + (((size_t)b*Hv + h)*Dv)*Sv;
    const unsigned short* lvbase = lvlt + (((size_t)b*8 + lt)*8)*256*16 + (size_t)t*16;

    const f32x4 fz = {0.f,0.f,0.f,0.f};
    const int R   = 3 - w;               // T2 rl-block (jb range matches T1's)
    const int llm = w*16 + cc;           // lane's score/softmax/P row
    const int sw  = (cc & 7) << 2;       // P column swizzle
    const int s_t2 = 4*g + cc;           // t2 mask helper
    const int Kb  = cc - 4*g + 63;       // t1 col base (minus 16*i)

    auto stage_k = [&](int r0){
        #pragma unroll
        for (int j = 0; j < 2; ++j){
            int row = w*16 + j*8 + lr8;
            int ch  = lc8 ^ (row & 7);
            gload16(kp + (size_t)(r0 + row)*64 + ch*8, ks + w*1024 + j*512);
        }
    };
    auto stage_de = [&](int r0){
        const int base = l0 - r0 + 448;
        #pragma unroll
        for (int j = 0; j < 4; ++j){
            int row = w*32 + j*8 + lr8;
            int gr = base + row; if (gr > 1022) gr = 1022;
            int ch  = lc8 ^ (row & 7);
            gload16(deb + (size_t)gr*64 + ch*8, des + w*2048 + j*512);
        }
    };
    auto stage_v0 = [&](){
        #pragma unroll
        for (int j = 0; j < 2; ++j){
            int row = w*16 + j*8 + lr8;
            int ch  = lc8 ^ (row & 7);
            gload16(vp + (size_t)row*512 + ch*8, vsq + w*1024 + j*512);
        }
    };

    // ---- prologue: Q frags from global; stage chunk-0
    bf8_t qf0, qf1;
    {
        int qrow = w*16 + cc;
        qf0 = *(const bf8_t*)(qp + (size_t)qrow*64 + g*8);
        qf1 = *(const bf8_t*)(qp + (size_t)qrow*64 + (g+4)*8);
    }
    stage_k(0); stage_de(0); stage_v0();
    __syncthreads();

    float l_run = 0.f;
    f32x4 ctx[4] = {fz,fz,fz,fz};

    for (int c8 = 0; c8 < 8; ++c8){
        const int r0 = c8 * 64;
        u16x8 lva = *(const u16x8*)(lvbase + (size_t)c8*256*16);
        u16x8 lvb = *(const u16x8*)(lvbase + (size_t)c8*256*16 + 8);

        // ---- MFMA phase: swapped scores + band with write2 scatters ----
        __builtin_amdgcn_s_setprio(1);
        f32x4 accs[4];                         // C[rl][ll]: rl=i16+4g+reg, ll=llm
        bf8_t kf0, kf1;
        #pragma unroll
        for (int i = 0; i < 4; ++i){
            int row = i*16 + cc;
            bf8_t b0 = *(const bf8_t*)&ks[row*64 + ((g       ^ (row & 7))*8)];
            bf8_t b1 = *(const bf8_t*)&ks[row*64 + (((g + 4) ^ (row & 7))*8)];
            if (i == R){ kf0 = b0; kf1 = b1; }
            f32x4 a = fz;
            a = __builtin_amdgcn_mfma_f32_16x16x32_bf16(b0, qf0, a, 0,0,0);
            a = __builtin_amdgcn_mfma_f32_16x16x32_bf16(b1, qf1, a, 0,0,0);
            accs[i] = a;
        }
        #pragma unroll
        for (int i = 0; i < 5; ++i){
            int jrow = (w + i)*16 + cc;
            bf8_t d0 = *(const bf8_t*)&des[jrow*64 + ((g       ^ (jrow & 7))*8)];
            bf8_t d1 = *(const bf8_t*)&des[jrow*64 + (((g + 4) ^ (jrow & 7))*8)];
            f32x4 a1 = fz, a2 = fz;                 // a1=C[jb][ll], a2=C[rl][jb]
            a1 = __builtin_amdgcn_mfma_f32_16x16x32_bf16(d0, qf0, a1, 0,0,0);
            a1 = __builtin_amdgcn_mfma_f32_16x16x32_bf16(d1, qf1, a1, 0,0,0);
            a2 = __builtin_amdgcn_mfma_f32_16x16x32_bf16(kf0, d0, a2, 0,0,0);
            a2 = __builtin_amdgcn_mfma_f32_16x16x32_bf16(kf1, d1, a2, 0,0,0);

            // t1 scatter (transposed): t1t[llm][rl], rl = K - reg
            {
                int K = Kb - 16*i;
                float* tb = t1t + llm*68 + K;
                bool mA = (i != 0 || K <= 64) && (i != 4 || K >= 0);
                bool mB = (i != 0 || K <= 66) && (i != 4 || K >= 2);
                if (mA){ tb[-1] = a1[1]; tb[0]  = a1[0]; }
                if (mB){ tb[-3] = a1[3]; tb[-2] = a1[2]; }
            }
            // t2 scatter: row = rl, col = (rl + jb - 63) + 1 (verified R9)
            {
                float* tb = t2c + (R*16 + 4*g)*66 + (16*i + 4*g + cc - 14);
                bool mA = (i != 0 || s_t2 >= 14) && (i != 4 || s_t2 <= 14);
                bool mB = (i != 0 || s_t2 >= 12) && (i != 4 || s_t2 <= 12);
                if (mA){ tb[0]   = a2[0]; tb[67]  = a2[1]; }
                if (mB){ tb[134] = a2[2]; tb[201] = a2[3]; }
            }
        }
        __builtin_amdgcn_s_setprio(0);
        __syncthreads();                       // B3: band visible; ks/des dead

        // issue next-chunk staging: K/DE direct-to-LDS, V to registers (T14)
        u16x8 pv0, pv1;
        if (c8 < 7){
            stage_k(r0 + 64); stage_de(r0 + 64);
            int row0 = w*16 + lr8,  ch0 = lc8 ^ (row0 & 7);
            int row1 = row0 + 8,    ch1 = lc8 ^ (row1 & 7);
            pv0 = *(const u16x8*)(vp + (size_t)row0*512 + (r0+64) + ch0*8);
            pv1 = *(const u16x8*)(vp + (size_t)row1*512 + (r0+64) + ch1*8);
        }

        // ---- epilogue: b128 t1 gathers, read2 t2 gathers, exp2, packed P ----
        float ps = 0.f;
        #pragma unroll
        for (int i = 0; i < 4; ++i){
            f32x4 t1v = *(const f32x4*)&t1t[llm*68 + 16*i + 4*g];
            const float* g2 = t2c + (i*16 + 4*g)*66 + llm + 1;
            float t20 = g2[0], t21 = g2[66], t22 = g2[132], t23 = g2[198];
            float lv0 = b2f(i < 2 ? (unsigned short)lva[i*4+0] : (unsigned short)lvb[(i-2)*4+0]);
            float lv1 = b2f(i < 2 ? (unsigned short)lva[i*4+1] : (unsigned short)lvb[(i-2)*4+1]);
            float lv2 = b2f(i < 2 ? (unsigned short)lva[i*4+2] : (unsigned short)lvb[(i-2)*4+2]);
            float lv3 = b2f(i < 2 ? (unsigned short)lva[i*4+3] : (unsigned short)lvb[(i-2)*4+3]);
            float p0 = __builtin_amdgcn_exp2f((accs[i][0] + t1v[0] + t20) * RS + lv0);
            float p1 = __builtin_amdgcn_exp2f((accs[i][1] + t1v[1] + t21) * RS + lv1);
            float p2 = __builtin_amdgcn_exp2f((accs[i][2] + t1v[2] + t22) * RS + lv2);
            float p3 = __builtin_amdgcn_exp2f((accs[i][3] + t1v[3] + t23) * RS + lv3);
            ps += (p0 + p1) + (p2 + p3);
            unsigned int prs0 = (unsigned)f2b(p0) | ((unsigned)f2b(p1) << 16);
            unsigned int prs1 = (unsigned)f2b(p2) | ((unsigned)f2b(p3) << 16);
            uint2 pr = { prs0, prs1 };
            *(uint2*)&Pb[llm*32 + ((i*8 + 2*g) ^ sw)] = pr;
        }
        ps += __shfl_xor(ps, 16);
        ps += __shfl_xor(ps, 32);
        l_run += ps;
        __builtin_amdgcn_wave_barrier();       // keep P writes before PV reads

        // ---- PV: A = P (packed, swizzled), B = V ----
        __builtin_amdgcn_s_setprio(1);
        #pragma unroll
        for (int kh = 0; kh < 2; ++kh){
            bf8_t pf = *(const bf8_t*)&Pb[llm*32 + ((16*kh + 4*g) ^ sw)];
            #pragma unroll
            for (int nf = 0; nf < 4; ++nf){
                int vr = nf*16 + cc;
                bf8_t vf = *(const bf8_t*)&vsq[vr*64 + (((g + 4*kh) ^ (vr & 7))*8)];
                ctx[nf] = __builtin_amdgcn_mfma_f32_16x16x32_bf16(pf, vf, ctx[nf], 0,0,0);
            }
        }
        __builtin_amdgcn_s_setprio(0);

        if (c8 < 7){
            __syncthreads();                   // B1: PV done; K/DE gloads drained
            *(u16x8*)&vsq[w*1024 +       lane*8] = pv0;
            *(u16x8*)&vsq[w*1024 + 512 + lane*8] = pv1;
            __syncthreads();                   // B2: new V visible
        }
    }

    // redistribute l_run (per-cc row sums) to the ctx row layout (4g+reg)
    float linv[4];
    #pragma unroll
    for (int reg = 0; reg < 4; ++reg)
        linv[reg] = 1.0f / __shfl(l_run, 4*g + reg);

    #pragma unroll
    for (int nf = 0; nf < 4; ++nf){
        #pragma unroll
        for (int reg = 0; reg < 4; ++reg){
            int ll = w*16 + 4*g + reg;
            out[((size_t)b*Sv + l0 + ll)*HIDv + h*64 + nf*16 + cc] = ctx[nf][reg] * linv[reg];
        }
    }
}

extern "C" void kernel_launch(void* const* d_in, const int* in_sizes, int n_in,
                              void* d_out, int out_size, void* d_ws, size_t ws_size,
                              hipStream_t stream)
{
    const float* hs   = (const float*)d_in[0];
    const float* mask = (const float*)d_in[1];
    const int*   cmat = (const int*)  d_in[2];
    const int*   wmat = (const int*)  d_in[3];
    const float* Wq   = (const float*)d_in[4];
    const float* bq   = (const float*)d_in[5];
    const float* Wk   = (const float*)d_in[6];
    const float* bk   = (const float*)d_in[7];
    const float* Wv   = (const float*)d_in[8];
    const float* bv   = (const float*)d_in[9];
    const float* de   = (const float*)d_in[10];
    const float* ce   = (const float*)d_in[11];
    const float* we   = (const float*)d_in[12];
    float* out = (float*)d_out;

    unsigned short* Xb   = (unsigned short*)d_ws;        // 8192*768
    unsigned short* Wb   = Xb   + 6291456;               // 2304*768
    unsigned short* deb  = Wb   + 1769472;               // 1023*64 (+ pad)
    unsigned short* qkb  = deb  + 65536;                 // 2*16*12*512*64
    unsigned short* vtb  = qkb  + 12582912;              // 16*12*64*512
    unsigned short* lvlt = vtb  + 6291456;               // 1024*256*16

    cvt_all<<<3840, 256, 0, stream>>>(hs, Wq, Wk, Wv, de, Xb, Wb, deb);
    prep_bias_t<<<1024, 256, 0, stream>>>(cmat, wmat, mask, ce, we, lvlt);
    qkv_gemm<<<dim3(64, 18), 256, 0, stream>>>(Xb, Wb, bq, bk, bv, qkb, vtb);
    attn<<<1536, 256, 0, stream>>>(qkb, vtb, deb, lvlt, out);
}